// Round 2
// baseline (563.502 us; speedup 1.0000x reference)
//
#include <hip/hip_runtime.h>

typedef _Float16 f16;
typedef _Float16 f16x8 __attribute__((ext_vector_type(8)));
typedef _Float16 f16x4 __attribute__((ext_vector_type(4)));
typedef float f32x4 __attribute__((ext_vector_type(4)));

#define B_ 2
#define T_ 2048
#define D_ 2048
#define H_ 16
#define DH_ 128

// ---------------------------------------------------------------------------
// fp32 -> fp16 elementwise cast (vectorized float4 -> f16x4)
// ---------------------------------------------------------------------------
__global__ void f32_to_f16_k(const float* __restrict__ in, f16* __restrict__ out, int n4) {
    int i = blockIdx.x * blockDim.x + threadIdx.x;
    if (i < n4) {
        float4 v = *((const float4*)in + i);
        f16x4 h;
        h[0] = (f16)v.x; h[1] = (f16)v.y; h[2] = (f16)v.z; h[3] = (f16)v.w;
        *((f16x4*)out + i) = h;
    }
}

// ---------------------------------------------------------------------------
// fp32 [R][C] -> fp16 [C][R] tiled transpose (32x32 tiles, LDS stride 33)
// ---------------------------------------------------------------------------
__global__ void transpose_f32_to_f16_k(const float* __restrict__ in, f16* __restrict__ out,
                                       int R, int C) {
    __shared__ float tile[32][33];
    int c0 = blockIdx.x * 32, r0 = blockIdx.y * 32;
    int tx = threadIdx.x, ty = threadIdx.y; // 32 x 8
#pragma unroll
    for (int j = 0; j < 4; j++)
        tile[ty + j * 8][tx] = in[(size_t)(r0 + ty + j * 8) * C + c0 + tx];
    __syncthreads();
#pragma unroll
    for (int j = 0; j < 4; j++)
        out[(size_t)(c0 + ty + j * 8) * R + r0 + tx] = (f16)tile[tx][ty + j * 8];
}

// ---------------------------------------------------------------------------
// GEMM: C[M][N] = A[M][2048] @ Bt[N][2048]^T  (m97 structure: 128x128 tile,
// 4 waves, BK=32, global_load_lds width-16, mfma_f32_16x16x32_f16)
// MODE 0: QKV epilogue (bias; route to Q(scaled)[B,H,T,Dh], K[B,H,T,Dh],
//         V transposed -> [B,H,Dh,T], all f16)
// MODE 1: out-proj epilogue (bias, fp32 store to d_out)
// ---------------------------------------------------------------------------
__device__ __forceinline__ void gload_lds16(const f16* g, f16* l) {
    __builtin_amdgcn_global_load_lds(
        (const __attribute__((address_space(1))) void*)g,
        (__attribute__((address_space(3))) void*)l, 16, 0, 0);
}

template <int MODE>
__global__ __launch_bounds__(256) void gemm_k(
    const f16* __restrict__ A, const f16* __restrict__ Bt,
    const float* __restrict__ bias,
    f16* __restrict__ Qo, f16* __restrict__ Ko, f16* __restrict__ Vto,
    float* __restrict__ Co) {
    const int m0 = blockIdx.y * 128, n0 = blockIdx.x * 128;
    const int tid = threadIdx.x;
    const int w = tid >> 6, lane = tid & 63;
    const int wr = w >> 1, wc = w & 1;
    const int lr = lane & 15, hi = lane >> 4, lk8 = (lane >> 4) * 8;
    const int srow = lane >> 2, scol = (lane & 3) * 8;

    __shared__ f16 As[128][32];
    __shared__ f16 Bs[128][32];

    f32x4 acc[4][4] = {};

    const f16* Ab = A + (size_t)m0 * 2048;
    const f16* Bb = Bt + (size_t)n0 * 2048;

    for (int k0 = 0; k0 < 2048; k0 += 32) {
        __syncthreads();
#pragma unroll
        for (int c = 0; c < 2; c++) {
            int ch = w * 2 + c; // 0..7, 16 rows each
            gload_lds16(Ab + (size_t)(ch * 16 + srow) * 2048 + k0 + scol, &As[ch * 16][0]);
            gload_lds16(Bb + (size_t)(ch * 16 + srow) * 2048 + k0 + scol, &Bs[ch * 16][0]);
        }
        __syncthreads();
        f16x8 a[4], b[4];
#pragma unroll
        for (int m = 0; m < 4; m++) a[m] = *(const f16x8*)&As[wr * 64 + m * 16 + lr][lk8];
#pragma unroll
        for (int n = 0; n < 4; n++) b[n] = *(const f16x8*)&Bs[wc * 64 + n * 16 + lr][lk8];
#pragma unroll
        for (int m = 0; m < 4; m++)
#pragma unroll
            for (int n = 0; n < 4; n++)
                acc[m][n] = __builtin_amdgcn_mfma_f32_16x16x32_f16(a[m], b[n], acc[m][n], 0, 0, 0);
    }

    const float qscale = 0.08838834764831845f; // 1/sqrt(128)
#pragma unroll
    for (int m = 0; m < 4; m++) {
        int row_l = wr * 64 + m * 16 + hi * 4;
#pragma unroll
        for (int n = 0; n < 4; n++) {
            int col = n0 + wc * 64 + n * 16 + lr;
            float bv = bias[col];
#pragma unroll
            for (int i = 0; i < 4; i++) {
                int row = m0 + row_l + i;
                float v = acc[m][n][i] + bv;
                if (MODE == 0) {
                    int s = col >> 11;
                    int r = col & 2047;
                    int h = r >> 7, dh = r & 127;
                    int bb = row >> 11, t = row & 2047;
                    if (s == 0) {
                        Qo[((size_t)(bb * H_ + h) * T_ + t) * DH_ + dh] = (f16)(v * qscale);
                    } else if (s == 1) {
                        Ko[((size_t)(bb * H_ + h) * T_ + t) * DH_ + dh] = (f16)v;
                    } else {
                        // V stored transposed: [B,H,Dh,T]
                        Vto[((size_t)(bb * H_ + h) * DH_ + dh) * T_ + t] = (f16)v;
                    }
                } else {
                    Co[(size_t)row * 2048 + col] = v;
                }
            }
        }
    }
}

// ---------------------------------------------------------------------------
// Flash attention (causal). 4 independent waves per block; each wave owns 32
// q-rows (two 16-row A-fragments) of one (b,h). KBLK=32. K/V read from global
// (L2/L3-resident); K and V fragments are reused across both q-fragments.
// S layout from mfma: s[r][i] = S[q = q0+r*16+hi*4+i][k = kt+lr] (+16 for s1).
// P staged to wave-private LDS (padded stride 40 f16 = 80B -> 2-way max bank
// aliasing on the b128 re-read, which is free per m136), re-read as the
// A-fragment for PV.
// ---------------------------------------------------------------------------
__global__ __launch_bounds__(256) void attn_k(
    const f16* __restrict__ Q, const f16* __restrict__ K,
    const f16* __restrict__ Vt, f16* __restrict__ O) {
    const int tid = threadIdx.x;
    const int w = tid >> 6, lane = tid & 63;
    const int gw = blockIdx.x * 4 + w;   // 0..2047
    const int bh = gw >> 6;              // T_/32 = 64 q-tiles per (b,h)
    const int qt = gw & 63;
    const int q0 = qt * 32;
    const int lr = lane & 15, hi = lane >> 4, lk8 = hi * 8;
    const int r0 = hi * 4;

    const f16* Qp = Q + (size_t)bh * T_ * DH_;
    const f16* Kp = K + (size_t)bh * T_ * DH_;
    const f16* Vp = Vt + (size_t)bh * DH_ * T_; // [Dh][T]

    __shared__ f16 Sl[4][32][40];

    f16x8 qf[2][4];
#pragma unroll
    for (int r = 0; r < 2; r++)
#pragma unroll
        for (int kc = 0; kc < 4; kc++)
            qf[r][kc] = *(const f16x8*)&Qp[(size_t)(q0 + r * 16 + lr) * DH_ + kc * 32 + lk8];

    f32x4 accO[2][8] = {};
    float mrun[2][4], lrun[2][4];
#pragma unroll
    for (int r = 0; r < 2; r++)
#pragma unroll
        for (int i = 0; i < 4; i++) { mrun[r][i] = -1e30f; lrun[r][i] = 0.f; }

    for (int kt = 0; kt <= q0; kt += 32) {
        f32x4 s0[2] = {}, s1[2] = {};
#pragma unroll
        for (int kc = 0; kc < 4; kc++) {
            f16x8 kf0 = *(const f16x8*)&Kp[(size_t)(kt + lr) * DH_ + kc * 32 + lk8];
            f16x8 kf1 = *(const f16x8*)&Kp[(size_t)(kt + 16 + lr) * DH_ + kc * 32 + lk8];
#pragma unroll
            for (int r = 0; r < 2; r++) {
                s0[r] = __builtin_amdgcn_mfma_f32_16x16x32_f16(qf[r][kc], kf0, s0[r], 0, 0, 0);
                s1[r] = __builtin_amdgcn_mfma_f32_16x16x32_f16(qf[r][kc], kf1, s1[r], 0, 0, 0);
            }
        }
        if (kt == q0) { // diagonal tile: causal mask
#pragma unroll
            for (int r = 0; r < 2; r++)
#pragma unroll
                for (int i = 0; i < 4; i++) {
                    int row = q0 + r * 16 + r0 + i;
                    if (kt + lr > row)      s0[r][i] = -1e30f;
                    if (kt + 16 + lr > row) s1[r][i] = -1e30f;
                }
        }
#pragma unroll
        for (int r = 0; r < 2; r++) {
            float fac[4];
#pragma unroll
            for (int i = 0; i < 4; i++) {
                float t = fmaxf(s0[r][i], s1[r][i]);
                t = fmaxf(t, __shfl_xor(t, 1));
                t = fmaxf(t, __shfl_xor(t, 2));
                t = fmaxf(t, __shfl_xor(t, 4));
                t = fmaxf(t, __shfl_xor(t, 8));
                float mnew = fmaxf(mrun[r][i], t);
                fac[i] = __expf(mrun[r][i] - mnew);
                mrun[r][i] = mnew;
                float p0 = __expf(s0[r][i] - mnew);
                float p1 = __expf(s1[r][i] - mnew);
                s0[r][i] = p0;
                s1[r][i] = p1;
                float rs = p0 + p1;
                rs += __shfl_xor(rs, 1);
                rs += __shfl_xor(rs, 2);
                rs += __shfl_xor(rs, 4);
                rs += __shfl_xor(rs, 8);
                lrun[r][i] = lrun[r][i] * fac[i] + rs;
                // stage P
                Sl[w][r * 16 + r0 + i][lr]      = (f16)p0;
                Sl[w][r * 16 + r0 + i][lr + 16] = (f16)p1;
            }
#pragma unroll
            for (int n = 0; n < 8; n++)
#pragma unroll
                for (int i = 0; i < 4; i++) accO[r][n][i] *= fac[i];
        }
        f16x8 pa[2];
#pragma unroll
        for (int r = 0; r < 2; r++) pa[r] = *(const f16x8*)&Sl[w][r * 16 + lr][lk8];
#pragma unroll
        for (int n = 0; n < 8; n++) {
            f16x8 vf = *(const f16x8*)&Vp[(size_t)(n * 16 + lr) * T_ + kt + lk8];
#pragma unroll
            for (int r = 0; r < 2; r++)
                accO[r][n] = __builtin_amdgcn_mfma_f32_16x16x32_f16(pa[r], vf, accO[r][n], 0, 0, 0);
        }
    }

    const int bb = bh >> 4, h = bh & 15;
#pragma unroll
    for (int r = 0; r < 2; r++)
#pragma unroll
        for (int n = 0; n < 8; n++)
#pragma unroll
            for (int i = 0; i < 4; i++) {
                float v = accO[r][n][i] / lrun[r][i];
                O[((size_t)(bb * T_ + q0 + r * 16 + r0 + i)) * D_ + h * DH_ + n * 16 + lr] = (f16)v;
            }
}

// ---------------------------------------------------------------------------
extern "C" void kernel_launch(void* const* d_in, const int* in_sizes, int n_in,
                              void* d_out, int out_size, void* d_ws, size_t ws_size,
                              hipStream_t stream) {
    const float* x    = (const float*)d_in[0];
    const float* Wqkv = (const float*)d_in[1];
    const float* bqkv = (const float*)d_in[2];
    const float* Wout = (const float*)d_in[3];
    const float* bout = (const float*)d_in[4];
    float* out = (float*)d_out;

    char* ws = (char*)d_ws;
    // layout (bytes):
    f16* xh    = (f16*)(ws);                    // 16 MB  [4096][2048]   (reused as O)
    f16* wqkvt = (f16*)(ws + 16777216);         // 24 MB  [6144][2048]
    f16* woutt = (f16*)(ws + 41943040);         //  8 MB  [2048][2048]
    f16* Qb    = (f16*)(ws + 50331648);         // 16 MB  [B,H,T,Dh]
    f16* Kb    = (f16*)(ws + 67108864);         // 16 MB  [B,H,T,Dh]
    f16* Vtb   = (f16*)(ws + 83886080);         // 16 MB  [B,H,Dh,T]
    f16* Oh    = xh;                            // alias: x_h dead after QKV GEMM

    // 1. casts / weight transposes
    f32_to_f16_k<<<8192, 256, 0, stream>>>(x, xh, (B_ * T_ * D_) / 4);
    transpose_f32_to_f16_k<<<dim3(192, 64), dim3(32, 8), 0, stream>>>(Wqkv, wqkvt, 2048, 6144);
    transpose_f32_to_f16_k<<<dim3(64, 64), dim3(32, 8), 0, stream>>>(Wout, woutt, 2048, 2048);

    // 2. QKV projection -> Q(scaled)/K [B,H,T,Dh], V [B,H,Dh,T]
    gemm_k<0><<<dim3(48, 32), 256, 0, stream>>>(xh, wqkvt, bqkv, Qb, Kb, Vtb, nullptr);

    // 3. causal flash attention -> O [B,T,D] f16
    attn_k<<<512, 256, 0, stream>>>(Qb, Kb, Vtb, Oh);

    // 4. output projection -> d_out fp32
    gemm_k<1><<<dim3(16, 32), 256, 0, stream>>>(Oh, woutt, bout, nullptr, nullptr, nullptr, out);
}